// Round 8
// baseline (471.732 us; speedup 1.0000x reference)
//
#include <hip/hip_runtime.h>
#include <math.h>

#define NN 100000
#define NE 3200000
#define NB 196          // dst-buckets of 512 nodes: 196*512 = 100352 >= NN
#define NP (NB * 512)   // pos space (100352)
#define CAPB 20480      // bin entries per bucket (mean 16327 + margin)
#define CAPE 26624      // csr slots per bucket (edges + <=15 pad/row: <=24600 hard)
#define EPB 8192        // edges per k_bin slab

typedef _Float16 half4 __attribute__((ext_vector_type(4)));

// Processing order = degree-sorted within each 512-node bucket (perm[pos] -> node).
// rc[pos] = (csr row start, deg); rows padded to x16 with sentinel NN.
// g (node space, NN+1 rows of 64 B fp16, pre-scaled by dis, row NN = zeros).
// ni (pos space, coalesced).

// ---------------- binned CSR build ----------------

__global__ __launch_bounds__(512) void k_init_gcur(int* gcur) {
    int i = threadIdx.x;
    if (i < NB) gcur[i] = i * CAPB;
}

__global__ __launch_bounds__(512) void k_bin(const int* __restrict__ src,
                                             const int* __restrict__ dst,
                                             int* __restrict__ gcur,
                                             unsigned* __restrict__ bin) {
    __shared__ int hist[NB];
    __shared__ int base[NB];
    int tid = threadIdx.x;
    for (int i = tid; i < NB; i += 512) hist[i] = 0;
    __syncthreads();
    int e0 = blockIdx.x * EPB;
    int dcache[EPB / 512];
#pragma unroll
    for (int i = 0; i < EPB / 512; i++) {
        int e = e0 + i * 512 + tid;
        dcache[i] = (e < NE) ? dst[e] : -1;
        if (dcache[i] >= 0) atomicAdd(&hist[dcache[i] >> 9], 1);
    }
    __syncthreads();
    for (int i = tid; i < NB; i += 512) {
        int c = hist[i];
        base[i] = (c > 0) ? atomicAdd(&gcur[i], c) : 0;
    }
    __syncthreads();
    for (int i = tid; i < NB; i += 512) hist[i] = 0;
    __syncthreads();
#pragma unroll
    for (int i = 0; i < EPB / 512; i++) {
        int e = e0 + i * 512 + tid;
        int d = dcache[i];
        if (d >= 0) {
            int b = d >> 9;
            int pos = base[b] + atomicAdd(&hist[b], 1);
            bin[pos] = ((unsigned)src[e] << 9) | (unsigned)(d & 511);
        }
    }
}

// Per-bucket: degree hist -> counting sort by degree -> row layout -> scatter.
// One kernel: bin slice (~64 KB) stays in L2 between the two passes.
__global__ __launch_bounds__(1024) void k_build(const int* __restrict__ gcur,
                                                const unsigned* __restrict__ bin,
                                                int2* __restrict__ rc,
                                                int* __restrict__ perm,
                                                int* __restrict__ csr) {
    __shared__ int deg[512];
    __shared__ int rank[512];
    __shared__ int dhist[128];
    __shared__ int dbase[128];
    __shared__ int sz[512];      // by rank: padded16 size -> inclusive scan
    __shared__ int rowst[512];   // by dl: absolute row start
    int b = blockIdx.x, tid = threadIdx.x;
    if (tid < 512) deg[tid] = 0;
    if (tid < 128) dhist[tid] = 0;
    __syncthreads();
    int base = b * CAPB, cnt = gcur[b] - base;
    for (int i = tid; i < cnt; i += 1024) atomicAdd(&deg[bin[base + i] & 511], 1);
    __syncthreads();
    int node = b * 512 + (tid & 511);
    int myDeg = 0, myKey = 127, myPad = 0;
    if (tid < 512) {
        myDeg = deg[tid];
        myKey = (node < NN) ? min(myDeg, 126) : 127;  // dead nodes sort last
        atomicAdd(&dhist[myKey], 1);
    }
    __syncthreads();
    if (tid == 0) {
        int run = 0;
        for (int i = 0; i < 128; i++) { int t = dhist[i]; dbase[i] = run; run += t; }
    }
    __syncthreads();
    if (tid < 128) dhist[tid] = 0;
    __syncthreads();
    if (tid < 512) {
        int r = dbase[myKey] + atomicAdd(&dhist[myKey], 1);
        rank[tid] = r;
        myPad = (node < NN) ? ((myDeg + 15) & ~15) : 0;
        sz[r] = myPad;
    }
    __syncthreads();
    for (int off = 1; off < 512; off <<= 1) {
        int t = 0;
        if (tid < 512 && tid >= off) t = sz[tid - off];
        __syncthreads();
        if (tid < 512) sz[tid] += t;
        __syncthreads();
    }
    if (tid < 512) {
        int excl = sz[rank[tid]] - myPad;
        int rs = b * CAPE + excl;
        rowst[tid] = rs;
        int pos = b * 512 + rank[tid];
        rc[pos] = make_int2(rs, (node < NN) ? myDeg : 0);
        perm[pos] = (node < NN) ? node : NN;
    }
    __syncthreads();
    if (tid < 512) deg[tid] = rowst[tid];   // reuse as cursors
    __syncthreads();
    for (int i = tid; i < cnt; i += 1024) {
        unsigned u = bin[base + i];
        int dl = u & 511;
        int pos = atomicAdd(&deg[dl], 1);
        csr[pos] = (int)(u >> 9);
    }
    __syncthreads();
    if (tid < 512 && node < NN) {
        int end = rowst[tid] + myPad;
        for (int i = deg[tid]; i < end; i++) csr[i] = NN;
    }
}

// ---------------- fused preproc (+ first GCN transform, pre-scaled) ----------------
__global__ __launch_bounds__(256) void k_preproc(
        const float* __restrict__ x,
        const float* __restrict__ W_pre, const float* __restrict__ b_pre,
        const float* __restrict__ W_fc1, const float* __restrict__ b_fc1,
        const float* __restrict__ W_fc2, const float* __restrict__ b_fc2,
        const float* __restrict__ W_gcn,
        const int* __restrict__ perm, const int2* __restrict__ rc,
        half4* __restrict__ ni, half4* __restrict__ g_out) {
    __shared__ __align__(16) float sWp[60];
    __shared__ __align__(16) float sbp[12];
    __shared__ __align__(16) float sW1[320];
    __shared__ __align__(16) float sb1[32];
    __shared__ __align__(16) float sW2[320];
    __shared__ __align__(16) float sb2[32];
    __shared__ __align__(16) float sWg[1024];
    __shared__ __align__(16) float s_h[32 * 36];
    int tid = threadIdx.x;
    if (tid < 60) sWp[tid] = W_pre[tid];
    if (tid >= 64 && tid < 74) sbp[tid - 64] = b_pre[tid - 64];
    for (int i = tid; i < 320; i += 256) { sW1[i] = W_fc1[i]; sW2[i] = W_fc2[i]; }
    if (tid >= 96 && tid < 128) sb1[tid - 96] = b_fc1[tid - 96];
    if (tid >= 128 && tid < 160) sb2[tid - 128] = b_fc2[tid - 128];
    for (int i = tid; i < 1024; i += 256) sWg[i] = W_gcn[i];
    __syncthreads();

    int ln = tid >> 3, q = tid & 7;
    int pos = blockIdx.x * 32 + ln;
    int n = perm[pos];
    int2 r = rc[pos];
    float dn = rsqrtf((float)r.y + 1.0f);
    int nx = (n < NN) ? n : 0;

    float xv[6];
#pragma unroll
    for (int k = 0; k < 6; k++) xv[k] = x[nx * 6 + k];
    float p[10];
#pragma unroll
    for (int j = 0; j < 10; j++) {
        float a = sbp[j];
#pragma unroll
        for (int k = 0; k < 6; k++) a = fmaf(xv[k], sWp[k * 10 + j], a);
        p[j] = 1.0f / (1.0f + expf(-a));
    }
    float4 a1 = ((const float4*)sb1)[q];
    float4 a2 = ((const float4*)sb2)[q];
#pragma unroll
    for (int k = 0; k < 10; k++) {
        float4 w1 = ((const float4*)sW1)[k * 8 + q];
        float4 w2 = ((const float4*)sW2)[k * 8 + q];
        a1.x = fmaf(p[k], w1.x, a1.x); a1.y = fmaf(p[k], w1.y, a1.y);
        a1.z = fmaf(p[k], w1.z, a1.z); a1.w = fmaf(p[k], w1.w, a1.w);
        a2.x = fmaf(p[k], w2.x, a2.x); a2.y = fmaf(p[k], w2.y, a2.y);
        a2.z = fmaf(p[k], w2.z, a2.z); a2.w = fmaf(p[k], w2.w, a2.w);
    }
    half4 niv;
    niv.x = (_Float16)fmaxf(a1.x, 0.f); niv.y = (_Float16)fmaxf(a1.y, 0.f);
    niv.z = (_Float16)fmaxf(a1.z, 0.f); niv.w = (_Float16)fmaxf(a1.w, 0.f);
    ni[pos * 8 + q] = niv;                        // pos space, coalesced
    float4 hv;
    hv.x = fmaxf(a2.x, 0.f); hv.y = fmaxf(a2.y, 0.f);
    hv.z = fmaxf(a2.z, 0.f); hv.w = fmaxf(a2.w, 0.f);
    *(float4*)&s_h[ln * 36 + 4 * q] = hv;
    __syncthreads();
    float4 o = make_float4(0.f, 0.f, 0.f, 0.f);
#pragma unroll
    for (int k = 0; k < 32; k++) {
        float v = s_h[ln * 36 + k];
        float4 wv = ((const float4*)sWg)[k * 8 + q];
        o.x = fmaf(v, wv.x, o.x); o.y = fmaf(v, wv.y, o.y);
        o.z = fmaf(v, wv.z, o.z); o.w = fmaf(v, wv.w, o.w);
    }
    if (n < NN) {
        half4 oh;
        oh.x = (_Float16)(o.x * dn); oh.y = (_Float16)(o.y * dn);
        oh.z = (_Float16)(o.z * dn); oh.w = (_Float16)(o.w * dn);
        g_out[n * 8 + q] = oh;                    // node space
    }
    if (blockIdx.x == 0 && tid < 8) {
        half4 z = (half4)(_Float16)0.f;
        g_out[NN * 8 + tid] = z;                  // zero sentinel row
    }
}

// ---------------- fused layer ----------------
template <bool LAST>
__global__ __launch_bounds__(256, 8) void k_layer(
        const half4* __restrict__ g_in,        // (NN+1) node rows, pre-scaled
        const int* __restrict__ csr,           // src ids, rows padded to x16
        const int2* __restrict__ rc,           // pos space
        const int* __restrict__ perm,          // pos -> node
        const half4* __restrict__ ni,          // pos space
        const float* __restrict__ W_dense, const float* __restrict__ b_dense,
        const float* __restrict__ b_gcn,
        const float* __restrict__ W2,          // LAST ? W_f1 : W_gcn
        const float* __restrict__ b_f1,
        const float* __restrict__ W_f2, const float* __restrict__ b_f2,
        void* __restrict__ out)                // LAST ? float logits : half4 g_out
{
    __shared__ __align__(16) float sWd[2048];
    __shared__ __align__(16) float sW2[LAST ? 2048 : 1024];
    __shared__ __align__(16) float sbd[32];
    __shared__ __align__(16) float sbg[32];
    __shared__ __align__(16) float sbf1[LAST ? 32 : 4];
    __shared__ __align__(16) float sWf2[LAST ? 64 : 4];
    __shared__ __align__(16) float sbf2[2];
    __shared__ __align__(16) _Float16 s_ni[32 * 36];
    __shared__ __align__(16) float s_t[32 * 36];

    int tid = threadIdx.x;
    for (int i = tid; i < 2048; i += 256) sWd[i] = W_dense[i];
    const int n2 = LAST ? 2048 : 1024;
    for (int i = tid; i < n2; i += 256) sW2[i] = W2[i];
    if (tid < 32) { sbd[tid] = b_dense[tid]; sbg[tid] = b_gcn[tid]; }
    if constexpr (LAST) {
        if (tid >= 64 && tid < 96) sbf1[tid - 64] = b_f1[tid - 64];
        if (tid >= 96 && tid < 160) sWf2[tid - 96] = W_f2[tid - 96];
        if (tid >= 160 && tid < 162) sbf2[tid - 160] = b_f2[tid - 160];
    }
    __syncthreads();

    int ln = tid >> 3, q = tid & 7;
    int pos = blockIdx.x * 32 + ln;
    int2 r = rc[pos];
    int start = r.x, cnt = r.y;
    int n = perm[pos];
    float disd = rsqrtf((float)cnt + 1.0f);

    // ---- gather: acc = g'[n] + sum g'[src]; t = relu(disd*acc + b) ----
    float4 acc;
    {
        half4 gs = g_in[n * 8 + q];
        acc.x = (float)gs.x; acc.y = (float)gs.y;
        acc.z = (float)gs.z; acc.w = (float)gs.w;
    }
    int nb16 = (cnt + 15) >> 4;
    for (int b = 0; b < nb16; b++) {
        int p = start + b * 16 + q;
        int s0 = __builtin_nontemporal_load(csr + p);
        int s1 = __builtin_nontemporal_load(csr + p + 8);
#pragma unroll
        for (int j = 0; j < 8; j++) {
            int s = __shfl(s0, j, 8);
            half4 gv = g_in[s * 8 + q];
            acc.x += (float)gv.x; acc.y += (float)gv.y;
            acc.z += (float)gv.z; acc.w += (float)gv.w;
        }
#pragma unroll
        for (int j = 0; j < 8; j++) {
            int s = __shfl(s1, j, 8);
            half4 gv = g_in[s * 8 + q];
            acc.x += (float)gv.x; acc.y += (float)gv.y;
            acc.z += (float)gv.z; acc.w += (float)gv.w;
        }
    }
    float4 t;
    t.x = fmaxf(fmaf(disd, acc.x, sbg[4 * q + 0]), 0.f);
    t.y = fmaxf(fmaf(disd, acc.y, sbg[4 * q + 1]), 0.f);
    t.z = fmaxf(fmaf(disd, acc.z, sbg[4 * q + 2]), 0.f);
    t.w = fmaxf(fmaf(disd, acc.w, sbg[4 * q + 3]), 0.f);
    *(float4*)&s_t[ln * 36 + 4 * q] = t;
    *(half4*)&s_ni[ln * 36 + 4 * q] = __builtin_nontemporal_load(&ni[pos * 8 + q]);
    __syncthreads();

    // ---- dense: h = relu(concat(ni, t) @ W_dense + b_dense) ----
    float4 a = ((const float4*)sbd)[q];
#pragma unroll
    for (int k = 0; k < 32; k++) {
        float v = (float)s_ni[ln * 36 + k];
        float4 wv = ((const float4*)sWd)[k * 8 + q];
        a.x = fmaf(v, wv.x, a.x); a.y = fmaf(v, wv.y, a.y);
        a.z = fmaf(v, wv.z, a.z); a.w = fmaf(v, wv.w, a.w);
    }
#pragma unroll
    for (int k = 0; k < 32; k++) {
        float v = s_t[ln * 36 + k];
        float4 wv = ((const float4*)sWd)[(32 + k) * 8 + q];
        a.x = fmaf(v, wv.x, a.x); a.y = fmaf(v, wv.y, a.y);
        a.z = fmaf(v, wv.z, a.z); a.w = fmaf(v, wv.w, a.w);
    }
    float4 h;
    h.x = fmaxf(a.x, 0.f); h.y = fmaxf(a.y, 0.f);
    h.z = fmaxf(a.z, 0.f); h.w = fmaxf(a.w, 0.f);
    __syncthreads();
    *(float4*)&s_t[ln * 36 + 4 * q] = h;
    __syncthreads();

    if constexpr (!LAST) {
        float4 o = make_float4(0.f, 0.f, 0.f, 0.f);
#pragma unroll
        for (int k = 0; k < 32; k++) {
            float v = s_t[ln * 36 + k];
            float4 wv = ((const float4*)sW2)[k * 8 + q];
            o.x = fmaf(v, wv.x, o.x); o.y = fmaf(v, wv.y, o.y);
            o.z = fmaf(v, wv.z, o.z); o.w = fmaf(v, wv.w, o.w);
        }
        if (n < NN) {
            half4 oh;
            oh.x = (_Float16)(o.x * disd); oh.y = (_Float16)(o.y * disd);
            oh.z = (_Float16)(o.z * disd); oh.w = (_Float16)(o.w * disd);
            ((half4*)out)[n * 8 + q] = oh;
        }
        if (blockIdx.x == 0 && tid < 8) {
            half4 z = (half4)(_Float16)0.f;
            ((half4*)out)[NN * 8 + tid] = z;
        }
    } else {
        float4 a2v = ((const float4*)sbf1)[q];
#pragma unroll
        for (int k = 0; k < 32; k++) {
            float v = (float)s_ni[ln * 36 + k];
            float4 wv = ((const float4*)sW2)[k * 8 + q];
            a2v.x = fmaf(v, wv.x, a2v.x); a2v.y = fmaf(v, wv.y, a2v.y);
            a2v.z = fmaf(v, wv.z, a2v.z); a2v.w = fmaf(v, wv.w, a2v.w);
        }
#pragma unroll
        for (int k = 0; k < 32; k++) {
            float v = s_t[ln * 36 + k];
            float4 wv = ((const float4*)sW2)[(32 + k) * 8 + q];
            a2v.x = fmaf(v, wv.x, a2v.x); a2v.y = fmaf(v, wv.y, a2v.y);
            a2v.z = fmaf(v, wv.z, a2v.z); a2v.w = fmaf(v, wv.w, a2v.w);
        }
        float4 u;
        u.x = fmaxf(a2v.x, 0.f); u.y = fmaxf(a2v.y, 0.f);
        u.z = fmaxf(a2v.z, 0.f); u.w = fmaxf(a2v.w, 0.f);
        float p0 = u.x * sWf2[(4 * q + 0) * 2 + 0] + u.y * sWf2[(4 * q + 1) * 2 + 0]
                 + u.z * sWf2[(4 * q + 2) * 2 + 0] + u.w * sWf2[(4 * q + 3) * 2 + 0];
        float p1 = u.x * sWf2[(4 * q + 0) * 2 + 1] + u.y * sWf2[(4 * q + 1) * 2 + 1]
                 + u.z * sWf2[(4 * q + 2) * 2 + 1] + u.w * sWf2[(4 * q + 3) * 2 + 1];
        p0 += __shfl_down(p0, 4, 8); p1 += __shfl_down(p1, 4, 8);
        p0 += __shfl_down(p0, 2, 8); p1 += __shfl_down(p1, 2, 8);
        p0 += __shfl_down(p0, 1, 8); p1 += __shfl_down(p1, 1, 8);
        if (q == 0 && n < NN) {
            ((float*)out)[n * 2 + 0] = p0 + sbf2[0];
            ((float*)out)[n * 2 + 1] = p1 + sbf2[1];
        }
    }
}

// ---------------- launch ----------------

extern "C" void kernel_launch(void* const* d_in, const int* in_sizes, int n_in,
                              void* d_out, int out_size, void* d_ws, size_t ws_size,
                              hipStream_t stream) {
    const float* x      = (const float*)d_in[0];
    const int*   ei     = (const int*)d_in[1];
    const float* W_pre  = (const float*)d_in[2];
    const float* b_pre  = (const float*)d_in[3];
    const float* W_fc1  = (const float*)d_in[4];
    const float* b_fc1  = (const float*)d_in[5];
    const float* W_fc2  = (const float*)d_in[6];
    const float* b_fc2  = (const float*)d_in[7];
    const float* W_gcn  = (const float*)d_in[8];
    const float* b_gcn  = (const float*)d_in[9];
    const float* W_dense= (const float*)d_in[10];
    const float* b_dense= (const float*)d_in[11];
    const float* W_f1   = (const float*)d_in[12];
    const float* b_f1   = (const float*)d_in[13];
    const float* W_f2   = (const float*)d_in[14];
    const float* b_f2   = (const float*)d_in[15];

    const int* src = ei;
    const int* dst = ei + NE;

    size_t off = 0;
    auto alloc = [&](size_t bytes) -> void* {
        off = (off + 255) & ~(size_t)255;
        void* p = (char*)d_ws + off;
        off += bytes;
        return p;
    };
    int2*  rc      = (int2*) alloc((size_t)NP * sizeof(int2));
    int*   perm    = (int*)  alloc((size_t)NP * sizeof(int));
    int*   gcur    = (int*)  alloc(NB * sizeof(int));
    int*   csr     = (int*)  alloc((size_t)NB * CAPE * sizeof(int));    // 20.9 MB
    // bin (16.05 MB) overlays gA+gB (2 x 6.4 MB fp16): bin dead before preproc.
    char*  Ureg    = (char*) alloc((size_t)NB * CAPB * sizeof(unsigned));
    half4* ni      = (half4*)alloc((size_t)NP * 32 * sizeof(_Float16));
    unsigned* bin  = (unsigned*)Ureg;
    half4* gA      = (half4*)Ureg;
    half4* gB      = (half4*)(Ureg + (size_t)(NN + 1) * 32 * sizeof(_Float16));

    const int binBlocks   = (NE + EPB - 1) / EPB; // 391
    const int fusedBlocks = NP / 32;              // 3136

    k_init_gcur<<<1, 512, 0, stream>>>(gcur);
    k_bin<<<binBlocks, 512, 0, stream>>>(src, dst, gcur, bin);
    k_build<<<NB, 1024, 0, stream>>>(gcur, bin, rc, perm, csr);

    k_preproc<<<fusedBlocks, 256, 0, stream>>>(x, W_pre, b_pre, W_fc1, b_fc1,
                                               W_fc2, b_fc2, W_gcn, perm, rc, ni, gA);

    half4* gin = gA;
    half4* gout = gB;
    for (int l = 0; l < 5; l++) {
        k_layer<false><<<fusedBlocks, 256, 0, stream>>>(
            gin, csr, rc, perm, ni, W_dense, b_dense, b_gcn,
            W_gcn, nullptr, nullptr, nullptr, (void*)gout);
        half4* tmp = gin; gin = gout; gout = tmp;
    }
    k_layer<true><<<fusedBlocks, 256, 0, stream>>>(
        gin, csr, rc, perm, ni, W_dense, b_dense, b_gcn,
        W_f1, b_f1, W_f2, b_f2, d_out);
}

// Round 9
// 454.813 us; speedup vs baseline: 1.0372x; 1.0372x over previous
//
#include <hip/hip_runtime.h>
#include <math.h>

#define NN 100000
#define NE 3200000
#define NB 196          // dst-buckets of 512 nodes: 196*512 = 100352 >= NN
#define NP (NB * 512)   // pos space (100352)
#define CAPB 20480      // bin entries per bucket (mean 16327 + margin)
#define CAPE 26624      // csr slots per bucket (edges + <=15 pad/row)
#define EPB 8192        // edges per k_bin slab
#define NBLK 3136       // layer grid (NP/32)

typedef _Float16 half4 __attribute__((ext_vector_type(4)));

// Degree-sorted pos space (perm[pos] -> node) with x16-padded rows (sentinel NN).
// Layer kernels use a balanced wave interleave: global wave k = pos [8k, 8k+8),
// assigned to block (k % NBLK), wave-slot (k / NBLK) -> uniform block durations.

// ---------------- binned CSR build ----------------

__global__ __launch_bounds__(512) void k_init_gcur(int* gcur) {
    int i = threadIdx.x;
    if (i < NB) gcur[i] = i * CAPB;
}

__global__ __launch_bounds__(512) void k_bin(const int* __restrict__ src,
                                             const int* __restrict__ dst,
                                             int* __restrict__ gcur,
                                             unsigned* __restrict__ bin) {
    __shared__ int hist[NB];
    __shared__ int base[NB];
    int tid = threadIdx.x;
    for (int i = tid; i < NB; i += 512) hist[i] = 0;
    __syncthreads();
    int e0 = blockIdx.x * EPB;
    int dcache[EPB / 512];
#pragma unroll
    for (int i = 0; i < EPB / 512; i++) {
        int e = e0 + i * 512 + tid;
        dcache[i] = (e < NE) ? dst[e] : -1;
        if (dcache[i] >= 0) atomicAdd(&hist[dcache[i] >> 9], 1);
    }
    __syncthreads();
    for (int i = tid; i < NB; i += 512) {
        int c = hist[i];
        base[i] = (c > 0) ? atomicAdd(&gcur[i], c) : 0;
    }
    __syncthreads();
    for (int i = tid; i < NB; i += 512) hist[i] = 0;
    __syncthreads();
#pragma unroll
    for (int i = 0; i < EPB / 512; i++) {
        int e = e0 + i * 512 + tid;
        int d = dcache[i];
        if (d >= 0) {
            int b = d >> 9;
            int pos = base[b] + atomicAdd(&hist[b], 1);
            bin[pos] = ((unsigned)src[e] << 9) | (unsigned)(d & 511);
        }
    }
}

// Per-bucket: degree hist -> counting sort by degree -> row layout -> scatter.
__global__ __launch_bounds__(1024) void k_build(const int* __restrict__ gcur,
                                                const unsigned* __restrict__ bin,
                                                int2* __restrict__ rc,
                                                int* __restrict__ perm,
                                                int* __restrict__ csr) {
    __shared__ int deg[512];
    __shared__ int rank[512];
    __shared__ int dhist[128];
    __shared__ int dbase[128];
    __shared__ int sz[512];
    __shared__ int rowst[512];
    int b = blockIdx.x, tid = threadIdx.x;
    if (tid < 512) deg[tid] = 0;
    if (tid < 128) dhist[tid] = 0;
    __syncthreads();
    int base = b * CAPB, cnt = gcur[b] - base;
    for (int i = tid; i < cnt; i += 1024) atomicAdd(&deg[bin[base + i] & 511], 1);
    __syncthreads();
    int node = b * 512 + (tid & 511);
    int myDeg = 0, myKey = 127, myPad = 0;
    if (tid < 512) {
        myDeg = deg[tid];
        myKey = (node < NN) ? min(myDeg, 126) : 127;
        atomicAdd(&dhist[myKey], 1);
    }
    __syncthreads();
    if (tid == 0) {
        int run = 0;
        for (int i = 0; i < 128; i++) { int t = dhist[i]; dbase[i] = run; run += t; }
    }
    __syncthreads();
    if (tid < 128) dhist[tid] = 0;
    __syncthreads();
    if (tid < 512) {
        int r = dbase[myKey] + atomicAdd(&dhist[myKey], 1);
        rank[tid] = r;
        myPad = (node < NN) ? ((myDeg + 15) & ~15) : 0;
        sz[r] = myPad;
    }
    __syncthreads();
    for (int off = 1; off < 512; off <<= 1) {
        int t = 0;
        if (tid < 512 && tid >= off) t = sz[tid - off];
        __syncthreads();
        if (tid < 512) sz[tid] += t;
        __syncthreads();
    }
    if (tid < 512) {
        int excl = sz[rank[tid]] - myPad;
        int rs = b * CAPE + excl;
        rowst[tid] = rs;
        int pos = b * 512 + rank[tid];
        rc[pos] = make_int2(rs, (node < NN) ? myDeg : 0);
        perm[pos] = (node < NN) ? node : NN;
    }
    __syncthreads();
    if (tid < 512) deg[tid] = rowst[tid];
    __syncthreads();
    for (int i = tid; i < cnt; i += 1024) {
        unsigned u = bin[base + i];
        int dl = u & 511;
        int pos = atomicAdd(&deg[dl], 1);
        csr[pos] = (int)(u >> 9);
    }
    __syncthreads();
    if (tid < 512 && node < NN) {
        int end = rowst[tid] + myPad;
        for (int i = deg[tid]; i < end; i++) csr[i] = NN;
    }
}

// ---------------- fused preproc (+ first GCN transform, pre-scaled) ----------------
__global__ __launch_bounds__(256) void k_preproc(
        const float* __restrict__ x,
        const float* __restrict__ W_pre, const float* __restrict__ b_pre,
        const float* __restrict__ W_fc1, const float* __restrict__ b_fc1,
        const float* __restrict__ W_fc2, const float* __restrict__ b_fc2,
        const float* __restrict__ W_gcn,
        const int* __restrict__ perm, const int2* __restrict__ rc,
        half4* __restrict__ ni, half4* __restrict__ g_out) {
    __shared__ __align__(16) float sWp[60];
    __shared__ __align__(16) float sbp[12];
    __shared__ __align__(16) float sW1[320];
    __shared__ __align__(16) float sb1[32];
    __shared__ __align__(16) float sW2[320];
    __shared__ __align__(16) float sb2[32];
    __shared__ __align__(16) float sWg[1024];
    __shared__ __align__(16) float s_h[32 * 36];
    int tid = threadIdx.x;
    if (tid < 60) sWp[tid] = W_pre[tid];
    if (tid >= 64 && tid < 74) sbp[tid - 64] = b_pre[tid - 64];
    for (int i = tid; i < 320; i += 256) { sW1[i] = W_fc1[i]; sW2[i] = W_fc2[i]; }
    if (tid >= 96 && tid < 128) sb1[tid - 96] = b_fc1[tid - 96];
    if (tid >= 128 && tid < 160) sb2[tid - 128] = b_fc2[tid - 128];
    for (int i = tid; i < 1024; i += 256) sWg[i] = W_gcn[i];
    __syncthreads();

    int ln = tid >> 3, q = tid & 7;
    int pos = blockIdx.x * 32 + ln;
    int n = perm[pos];
    int2 r = rc[pos];
    float dn = rsqrtf((float)r.y + 1.0f);
    int nx = (n < NN) ? n : 0;

    float xv[6];
#pragma unroll
    for (int k = 0; k < 6; k++) xv[k] = x[nx * 6 + k];
    float p[10];
#pragma unroll
    for (int j = 0; j < 10; j++) {
        float a = sbp[j];
#pragma unroll
        for (int k = 0; k < 6; k++) a = fmaf(xv[k], sWp[k * 10 + j], a);
        p[j] = 1.0f / (1.0f + expf(-a));
    }
    float4 a1 = ((const float4*)sb1)[q];
    float4 a2 = ((const float4*)sb2)[q];
#pragma unroll
    for (int k = 0; k < 10; k++) {
        float4 w1 = ((const float4*)sW1)[k * 8 + q];
        float4 w2 = ((const float4*)sW2)[k * 8 + q];
        a1.x = fmaf(p[k], w1.x, a1.x); a1.y = fmaf(p[k], w1.y, a1.y);
        a1.z = fmaf(p[k], w1.z, a1.z); a1.w = fmaf(p[k], w1.w, a1.w);
        a2.x = fmaf(p[k], w2.x, a2.x); a2.y = fmaf(p[k], w2.y, a2.y);
        a2.z = fmaf(p[k], w2.z, a2.z); a2.w = fmaf(p[k], w2.w, a2.w);
    }
    half4 niv;
    niv.x = (_Float16)fmaxf(a1.x, 0.f); niv.y = (_Float16)fmaxf(a1.y, 0.f);
    niv.z = (_Float16)fmaxf(a1.z, 0.f); niv.w = (_Float16)fmaxf(a1.w, 0.f);
    ni[pos * 8 + q] = niv;
    float4 hv;
    hv.x = fmaxf(a2.x, 0.f); hv.y = fmaxf(a2.y, 0.f);
    hv.z = fmaxf(a2.z, 0.f); hv.w = fmaxf(a2.w, 0.f);
    *(float4*)&s_h[ln * 36 + 4 * q] = hv;
    __syncthreads();
    float4 o = make_float4(0.f, 0.f, 0.f, 0.f);
#pragma unroll
    for (int k = 0; k < 32; k++) {
        float v = s_h[ln * 36 + k];
        float4 wv = ((const float4*)sWg)[k * 8 + q];
        o.x = fmaf(v, wv.x, o.x); o.y = fmaf(v, wv.y, o.y);
        o.z = fmaf(v, wv.z, o.z); o.w = fmaf(v, wv.w, o.w);
    }
    if (n < NN) {
        half4 oh;
        oh.x = (_Float16)(o.x * dn); oh.y = (_Float16)(o.y * dn);
        oh.z = (_Float16)(o.z * dn); oh.w = (_Float16)(o.w * dn);
        g_out[n * 8 + q] = oh;
    }
    if (blockIdx.x == 0 && tid < 8) {
        half4 z = (half4)(_Float16)0.f;
        g_out[NN * 8 + tid] = z;
    }
}

// ---------------- fused layer ----------------
template <bool LAST>
__global__ __launch_bounds__(256, 6) void k_layer(
        const half4* __restrict__ g_in,        // (NN+1) node rows, pre-scaled
        const int* __restrict__ csr,           // src ids, rows padded to x16
        const int2* __restrict__ rc,           // pos space
        const int* __restrict__ perm,          // pos -> node
        const half4* __restrict__ ni,          // pos space
        const float* __restrict__ W_dense, const float* __restrict__ b_dense,
        const float* __restrict__ b_gcn,
        const float* __restrict__ W2,          // LAST ? W_f1 : W_gcn
        const float* __restrict__ b_f1,
        const float* __restrict__ W_f2, const float* __restrict__ b_f2,
        void* __restrict__ out)                // LAST ? float logits : half4 g_out
{
    __shared__ __align__(16) float sWd[2048];
    __shared__ __align__(16) float sW2[LAST ? 2048 : 1024];
    __shared__ __align__(16) float sbd[32];
    __shared__ __align__(16) float sbg[32];
    __shared__ __align__(16) float sbf1[LAST ? 32 : 4];
    __shared__ __align__(16) float sWf2[LAST ? 64 : 4];
    __shared__ __align__(16) float sbf2[2];
    __shared__ __align__(16) _Float16 s_ni[32 * 36];
    __shared__ __align__(16) float s_t[32 * 36];

    int tid = threadIdx.x;
    for (int i = tid; i < 2048; i += 256) sWd[i] = W_dense[i];
    const int n2 = LAST ? 2048 : 1024;
    for (int i = tid; i < n2; i += 256) sW2[i] = W2[i];
    if (tid < 32) { sbd[tid] = b_dense[tid]; sbg[tid] = b_gcn[tid]; }
    if constexpr (LAST) {
        if (tid >= 64 && tid < 96) sbf1[tid - 64] = b_f1[tid - 64];
        if (tid >= 96 && tid < 160) sWf2[tid - 96] = W_f2[tid - 96];
        if (tid >= 160 && tid < 162) sbf2[tid - 160] = b_f2[tid - 160];
    }
    __syncthreads();

    int ln = tid >> 3, q = tid & 7;
    // balanced interleave: wave (tid>>6) of this block handles global wave id
    // blockIdx.x + (tid>>6)*NBLK; its 8 node-groups take consecutive sorted pos.
    int gw = blockIdx.x + (tid >> 6) * NBLK;
    int pos = gw * 8 + ((tid >> 3) & 7);
    int2 r = rc[pos];
    int start = r.x, cnt = r.y;
    int n = perm[pos];
    float disd = rsqrtf((float)cnt + 1.0f);

    // ---- gather: acc = g'[n] + sum g'[src]; t = relu(disd*acc + b) ----
    float4 acc;
    {
        half4 gs = g_in[n * 8 + q];
        acc.x = (float)gs.x; acc.y = (float)gs.y;
        acc.z = (float)gs.z; acc.w = (float)gs.w;
    }
    int nb16 = (cnt + 15) >> 4;
    for (int b = 0; b < nb16; b++) {
        int p = start + b * 16 + q;
        int s0 = __builtin_nontemporal_load(csr + p);
        int s1 = __builtin_nontemporal_load(csr + p + 8);
        half4 tmp[16];
#pragma unroll
        for (int j = 0; j < 8; j++) tmp[j] = g_in[__shfl(s0, j, 8) * 8 + q];
#pragma unroll
        for (int j = 0; j < 8; j++) tmp[8 + j] = g_in[__shfl(s1, j, 8) * 8 + q];
#pragma unroll
        for (int j = 0; j < 16; j++) {
            acc.x += (float)tmp[j].x; acc.y += (float)tmp[j].y;
            acc.z += (float)tmp[j].z; acc.w += (float)tmp[j].w;
        }
    }
    float4 t;
    t.x = fmaxf(fmaf(disd, acc.x, sbg[4 * q + 0]), 0.f);
    t.y = fmaxf(fmaf(disd, acc.y, sbg[4 * q + 1]), 0.f);
    t.z = fmaxf(fmaf(disd, acc.z, sbg[4 * q + 2]), 0.f);
    t.w = fmaxf(fmaf(disd, acc.w, sbg[4 * q + 3]), 0.f);
    *(float4*)&s_t[ln * 36 + 4 * q] = t;
    *(half4*)&s_ni[ln * 36 + 4 * q] = __builtin_nontemporal_load(&ni[pos * 8 + q]);
    __syncthreads();

    // ---- dense: h = relu(concat(ni, t) @ W_dense + b_dense) ----
    float4 a = ((const float4*)sbd)[q];
#pragma unroll
    for (int k = 0; k < 32; k++) {
        float v = (float)s_ni[ln * 36 + k];
        float4 wv = ((const float4*)sWd)[k * 8 + q];
        a.x = fmaf(v, wv.x, a.x); a.y = fmaf(v, wv.y, a.y);
        a.z = fmaf(v, wv.z, a.z); a.w = fmaf(v, wv.w, a.w);
    }
#pragma unroll
    for (int k = 0; k < 32; k++) {
        float v = s_t[ln * 36 + k];
        float4 wv = ((const float4*)sWd)[(32 + k) * 8 + q];
        a.x = fmaf(v, wv.x, a.x); a.y = fmaf(v, wv.y, a.y);
        a.z = fmaf(v, wv.z, a.z); a.w = fmaf(v, wv.w, a.w);
    }
    float4 h;
    h.x = fmaxf(a.x, 0.f); h.y = fmaxf(a.y, 0.f);
    h.z = fmaxf(a.z, 0.f); h.w = fmaxf(a.w, 0.f);
    __syncthreads();
    *(float4*)&s_t[ln * 36 + 4 * q] = h;
    __syncthreads();

    if constexpr (!LAST) {
        float4 o = make_float4(0.f, 0.f, 0.f, 0.f);
#pragma unroll
        for (int k = 0; k < 32; k++) {
            float v = s_t[ln * 36 + k];
            float4 wv = ((const float4*)sW2)[k * 8 + q];
            o.x = fmaf(v, wv.x, o.x); o.y = fmaf(v, wv.y, o.y);
            o.z = fmaf(v, wv.z, o.z); o.w = fmaf(v, wv.w, o.w);
        }
        if (n < NN) {
            half4 oh;
            oh.x = (_Float16)(o.x * disd); oh.y = (_Float16)(o.y * disd);
            oh.z = (_Float16)(o.z * disd); oh.w = (_Float16)(o.w * disd);
            ((half4*)out)[n * 8 + q] = oh;
        }
        if (blockIdx.x == 0 && tid < 8) {
            half4 z = (half4)(_Float16)0.f;
            ((half4*)out)[NN * 8 + tid] = z;
        }
    } else {
        float4 a2v = ((const float4*)sbf1)[q];
#pragma unroll
        for (int k = 0; k < 32; k++) {
            float v = (float)s_ni[ln * 36 + k];
            float4 wv = ((const float4*)sW2)[k * 8 + q];
            a2v.x = fmaf(v, wv.x, a2v.x); a2v.y = fmaf(v, wv.y, a2v.y);
            a2v.z = fmaf(v, wv.z, a2v.z); a2v.w = fmaf(v, wv.w, a2v.w);
        }
#pragma unroll
        for (int k = 0; k < 32; k++) {
            float v = s_t[ln * 36 + k];
            float4 wv = ((const float4*)sW2)[(32 + k) * 8 + q];
            a2v.x = fmaf(v, wv.x, a2v.x); a2v.y = fmaf(v, wv.y, a2v.y);
            a2v.z = fmaf(v, wv.z, a2v.z); a2v.w = fmaf(v, wv.w, a2v.w);
        }
        float4 u;
        u.x = fmaxf(a2v.x, 0.f); u.y = fmaxf(a2v.y, 0.f);
        u.z = fmaxf(a2v.z, 0.f); u.w = fmaxf(a2v.w, 0.f);
        float p0 = u.x * sWf2[(4 * q + 0) * 2 + 0] + u.y * sWf2[(4 * q + 1) * 2 + 0]
                 + u.z * sWf2[(4 * q + 2) * 2 + 0] + u.w * sWf2[(4 * q + 3) * 2 + 0];
        float p1 = u.x * sWf2[(4 * q + 0) * 2 + 1] + u.y * sWf2[(4 * q + 1) * 2 + 1]
                 + u.z * sWf2[(4 * q + 2) * 2 + 1] + u.w * sWf2[(4 * q + 3) * 2 + 1];
        p0 += __shfl_down(p0, 4, 8); p1 += __shfl_down(p1, 4, 8);
        p0 += __shfl_down(p0, 2, 8); p1 += __shfl_down(p1, 2, 8);
        p0 += __shfl_down(p0, 1, 8); p1 += __shfl_down(p1, 1, 8);
        if (q == 0 && n < NN) {
            ((float*)out)[n * 2 + 0] = p0 + sbf2[0];
            ((float*)out)[n * 2 + 1] = p1 + sbf2[1];
        }
    }
}

// ---------------- launch ----------------

extern "C" void kernel_launch(void* const* d_in, const int* in_sizes, int n_in,
                              void* d_out, int out_size, void* d_ws, size_t ws_size,
                              hipStream_t stream) {
    const float* x      = (const float*)d_in[0];
    const int*   ei     = (const int*)d_in[1];
    const float* W_pre  = (const float*)d_in[2];
    const float* b_pre  = (const float*)d_in[3];
    const float* W_fc1  = (const float*)d_in[4];
    const float* b_fc1  = (const float*)d_in[5];
    const float* W_fc2  = (const float*)d_in[6];
    const float* b_fc2  = (const float*)d_in[7];
    const float* W_gcn  = (const float*)d_in[8];
    const float* b_gcn  = (const float*)d_in[9];
    const float* W_dense= (const float*)d_in[10];
    const float* b_dense= (const float*)d_in[11];
    const float* W_f1   = (const float*)d_in[12];
    const float* b_f1   = (const float*)d_in[13];
    const float* W_f2   = (const float*)d_in[14];
    const float* b_f2   = (const float*)d_in[15];

    const int* src = ei;
    const int* dst = ei + NE;

    size_t off = 0;
    auto alloc = [&](size_t bytes) -> void* {
        off = (off + 255) & ~(size_t)255;
        void* p = (char*)d_ws + off;
        off += bytes;
        return p;
    };
    int2*  rc      = (int2*) alloc((size_t)NP * sizeof(int2));
    int*   perm    = (int*)  alloc((size_t)NP * sizeof(int));
    int*   gcur    = (int*)  alloc(NB * sizeof(int));
    int*   csr     = (int*)  alloc((size_t)NB * CAPE * sizeof(int));    // 20.9 MB
    // bin (16.05 MB) overlays gA+gB (2 x 6.4 MB fp16): bin dead before preproc.
    char*  Ureg    = (char*) alloc((size_t)NB * CAPB * sizeof(unsigned));
    half4* ni      = (half4*)alloc((size_t)NP * 32 * sizeof(_Float16));
    unsigned* bin  = (unsigned*)Ureg;
    half4* gA      = (half4*)Ureg;
    half4* gB      = (half4*)(Ureg + (size_t)(NN + 1) * 32 * sizeof(_Float16));

    const int binBlocks   = (NE + EPB - 1) / EPB; // 391

    k_init_gcur<<<1, 512, 0, stream>>>(gcur);
    k_bin<<<binBlocks, 512, 0, stream>>>(src, dst, gcur, bin);
    k_build<<<NB, 1024, 0, stream>>>(gcur, bin, rc, perm, csr);

    k_preproc<<<NBLK, 256, 0, stream>>>(x, W_pre, b_pre, W_fc1, b_fc1,
                                        W_fc2, b_fc2, W_gcn, perm, rc, ni, gA);

    half4* gin = gA;
    half4* gout = gB;
    for (int l = 0; l < 5; l++) {
        k_layer<false><<<NBLK, 256, 0, stream>>>(
            gin, csr, rc, perm, ni, W_dense, b_dense, b_gcn,
            W_gcn, nullptr, nullptr, nullptr, (void*)gout);
        half4* tmp = gin; gin = gout; gout = tmp;
    }
    k_layer<true><<<NBLK, 256, 0, stream>>>(
        gin, csr, rc, perm, ni, W_dense, b_dense, b_gcn,
        W_f1, b_f1, W_f2, b_f2, d_out);
}

// Round 10
// 431.599 us; speedup vs baseline: 1.0930x; 1.0538x over previous
//
#include <hip/hip_runtime.h>
#include <math.h>

#define NN 100000
#define NE 3200000
#define NB 196          // dst-buckets of 512 nodes: 196*512 = 100352 >= NN
#define NP (NB * 512)   // pos space (100352)
#define CAPB 20480      // bin entries per bucket (mean 16327 + 32 sigma)
#define CAPE 26624      // csr slots per bucket (edges + <=15 pad/row)
#define EPB 8192        // edges per k_bin slab
#define NBLK 3136       // layer grid (NP/32)
#define WPB 8           // waves per k_bin block

typedef _Float16 half4 __attribute__((ext_vector_type(4)));

// Degree-sorted pos space (perm[pos] -> node) with x16-padded rows (sentinel NN).
// Layers: balanced wave interleave (global wave k -> block k%NBLK, slot k/NBLK).
// csr/ni read WITHOUT nontemporal: re-read each layer, keep LLC-resident.

// ---------------- binned CSR build ----------------

__global__ __launch_bounds__(512) void k_init_gcur(int* gcur) {
    int i = threadIdx.x;
    if (i < NB) gcur[i] = i * CAPB;
}

// Per-wave split histograms: 8x less LDS-atomic contention in count & scatter.
__global__ __launch_bounds__(512) void k_bin(const int* __restrict__ src,
                                             const int* __restrict__ dst,
                                             int* __restrict__ gcur,
                                             unsigned* __restrict__ bin) {
    __shared__ int h8[WPB][NB];     // per-wave histogram / cursor
    __shared__ int b8[WPB][NB];     // per-wave scatter base
    int tid = threadIdx.x;
    int w = tid >> 6;
    for (int i = tid; i < WPB * NB; i += 512) ((int*)h8)[i] = 0;
    __syncthreads();
    int e0 = blockIdx.x * EPB;
    int dcache[EPB / 512];
#pragma unroll
    for (int i = 0; i < EPB / 512; i++) {
        int e = e0 + i * 512 + tid;
        dcache[i] = (e < NE) ? dst[e] : -1;
        if (dcache[i] >= 0) atomicAdd(&h8[w][dcache[i] >> 9], 1);
    }
    __syncthreads();
    // one global reservation per bucket; split into per-wave bases
    for (int b = tid; b < NB; b += 512) {
        int tot = 0;
#pragma unroll
        for (int ww = 0; ww < WPB; ww++) tot += h8[ww][b];
        int run = (tot > 0) ? atomicAdd(&gcur[b], tot) : 0;
#pragma unroll
        for (int ww = 0; ww < WPB; ww++) { b8[ww][b] = run; run += h8[ww][b]; }
    }
    __syncthreads();
    for (int i = tid; i < WPB * NB; i += 512) ((int*)h8)[i] = 0;
    __syncthreads();
#pragma unroll
    for (int i = 0; i < EPB / 512; i++) {
        int e = e0 + i * 512 + tid;
        int d = dcache[i];
        if (d >= 0) {
            int b = d >> 9;
            int pos = b8[w][b] + atomicAdd(&h8[w][b], 1);
            bin[pos] = ((unsigned)src[e] << 9) | (unsigned)(d & 511);
        }
    }
}

// Per-bucket: degree hist -> counting sort by degree -> row layout -> scatter.
__global__ __launch_bounds__(1024) void k_build(const int* __restrict__ gcur,
                                                const unsigned* __restrict__ bin,
                                                int2* __restrict__ rc,
                                                int* __restrict__ perm,
                                                int* __restrict__ csr) {
    __shared__ int deg[512];
    __shared__ int rank[512];
    __shared__ int dhist[128];
    __shared__ int dbase[128];
    __shared__ int sz[512];
    __shared__ int rowst[512];
    int b = blockIdx.x, tid = threadIdx.x;
    if (tid < 512) deg[tid] = 0;
    if (tid < 128) dhist[tid] = 0;
    __syncthreads();
    int base = b * CAPB, cnt = gcur[b] - base;
    for (int i = tid; i < cnt; i += 1024) atomicAdd(&deg[bin[base + i] & 511], 1);
    __syncthreads();
    int node = b * 512 + (tid & 511);
    int myDeg = 0, myKey = 127, myPad = 0;
    if (tid < 512) {
        myDeg = deg[tid];
        myKey = (node < NN) ? min(myDeg, 126) : 127;
        atomicAdd(&dhist[myKey], 1);
    }
    __syncthreads();
    // parallel exclusive scan over 128 degree-keys (Hillis-Steele)
    if (tid < 128) dbase[tid] = dhist[tid];
    __syncthreads();
    for (int off = 1; off < 128; off <<= 1) {
        int t = 0;
        if (tid < 128 && tid >= off) t = dbase[tid - off];
        __syncthreads();
        if (tid < 128) dbase[tid] += t;
        __syncthreads();
    }
    if (tid < 128) dbase[tid] -= dhist[tid];   // inclusive -> exclusive
    __syncthreads();
    if (tid < 128) dhist[tid] = 0;
    __syncthreads();
    if (tid < 512) {
        int r = dbase[myKey] + atomicAdd(&dhist[myKey], 1);
        rank[tid] = r;
        myPad = (node < NN) ? ((myDeg + 15) & ~15) : 0;
        sz[r] = myPad;
    }
    __syncthreads();
    for (int off = 1; off < 512; off <<= 1) {
        int t = 0;
        if (tid < 512 && tid >= off) t = sz[tid - off];
        __syncthreads();
        if (tid < 512) sz[tid] += t;
        __syncthreads();
    }
    if (tid < 512) {
        int excl = sz[rank[tid]] - myPad;
        int rs = b * CAPE + excl;
        rowst[tid] = rs;
        int pos = b * 512 + rank[tid];
        rc[pos] = make_int2(rs, (node < NN) ? myDeg : 0);
        perm[pos] = (node < NN) ? node : NN;
    }
    __syncthreads();
    if (tid < 512) deg[tid] = rowst[tid];
    __syncthreads();
    for (int i = tid; i < cnt; i += 1024) {
        unsigned u = bin[base + i];
        int dl = u & 511;
        int pos = atomicAdd(&deg[dl], 1);
        csr[pos] = (int)(u >> 9);
    }
    __syncthreads();
    if (tid < 512 && node < NN) {
        int end = rowst[tid] + myPad;
        for (int i = deg[tid]; i < end; i++) csr[i] = NN;
    }
}

// ---------------- fused preproc (+ first GCN transform, pre-scaled) ----------------
__global__ __launch_bounds__(256) void k_preproc(
        const float* __restrict__ x,
        const float* __restrict__ W_pre, const float* __restrict__ b_pre,
        const float* __restrict__ W_fc1, const float* __restrict__ b_fc1,
        const float* __restrict__ W_fc2, const float* __restrict__ b_fc2,
        const float* __restrict__ W_gcn,
        const int* __restrict__ perm, const int2* __restrict__ rc,
        half4* __restrict__ ni, half4* __restrict__ g_out) {
    __shared__ __align__(16) float sWp[60];
    __shared__ __align__(16) float sbp[12];
    __shared__ __align__(16) float sW1[320];
    __shared__ __align__(16) float sb1[32];
    __shared__ __align__(16) float sW2[320];
    __shared__ __align__(16) float sb2[32];
    __shared__ __align__(16) float sWg[1024];
    __shared__ __align__(16) float s_h[32 * 36];
    int tid = threadIdx.x;
    if (tid < 60) sWp[tid] = W_pre[tid];
    if (tid >= 64 && tid < 74) sbp[tid - 64] = b_pre[tid - 64];
    for (int i = tid; i < 320; i += 256) { sW1[i] = W_fc1[i]; sW2[i] = W_fc2[i]; }
    if (tid >= 96 && tid < 128) sb1[tid - 96] = b_fc1[tid - 96];
    if (tid >= 128 && tid < 160) sb2[tid - 128] = b_fc2[tid - 128];
    for (int i = tid; i < 1024; i += 256) sWg[i] = W_gcn[i];
    __syncthreads();

    int ln = tid >> 3, q = tid & 7;
    int pos = blockIdx.x * 32 + ln;
    int n = perm[pos];
    int2 r = rc[pos];
    float dn = rsqrtf((float)r.y + 1.0f);
    int nx = (n < NN) ? n : 0;

    float xv[6];
#pragma unroll
    for (int k = 0; k < 6; k++) xv[k] = x[nx * 6 + k];
    float p[10];
#pragma unroll
    for (int j = 0; j < 10; j++) {
        float a = sbp[j];
#pragma unroll
        for (int k = 0; k < 6; k++) a = fmaf(xv[k], sWp[k * 10 + j], a);
        p[j] = 1.0f / (1.0f + expf(-a));
    }
    float4 a1 = ((const float4*)sb1)[q];
    float4 a2 = ((const float4*)sb2)[q];
#pragma unroll
    for (int k = 0; k < 10; k++) {
        float4 w1 = ((const float4*)sW1)[k * 8 + q];
        float4 w2 = ((const float4*)sW2)[k * 8 + q];
        a1.x = fmaf(p[k], w1.x, a1.x); a1.y = fmaf(p[k], w1.y, a1.y);
        a1.z = fmaf(p[k], w1.z, a1.z); a1.w = fmaf(p[k], w1.w, a1.w);
        a2.x = fmaf(p[k], w2.x, a2.x); a2.y = fmaf(p[k], w2.y, a2.y);
        a2.z = fmaf(p[k], w2.z, a2.z); a2.w = fmaf(p[k], w2.w, a2.w);
    }
    half4 niv;
    niv.x = (_Float16)fmaxf(a1.x, 0.f); niv.y = (_Float16)fmaxf(a1.y, 0.f);
    niv.z = (_Float16)fmaxf(a1.z, 0.f); niv.w = (_Float16)fmaxf(a1.w, 0.f);
    ni[pos * 8 + q] = niv;
    float4 hv;
    hv.x = fmaxf(a2.x, 0.f); hv.y = fmaxf(a2.y, 0.f);
    hv.z = fmaxf(a2.z, 0.f); hv.w = fmaxf(a2.w, 0.f);
    *(float4*)&s_h[ln * 36 + 4 * q] = hv;
    __syncthreads();
    float4 o = make_float4(0.f, 0.f, 0.f, 0.f);
#pragma unroll
    for (int k = 0; k < 32; k++) {
        float v = s_h[ln * 36 + k];
        float4 wv = ((const float4*)sWg)[k * 8 + q];
        o.x = fmaf(v, wv.x, o.x); o.y = fmaf(v, wv.y, o.y);
        o.z = fmaf(v, wv.z, o.z); o.w = fmaf(v, wv.w, o.w);
    }
    if (n < NN) {
        half4 oh;
        oh.x = (_Float16)(o.x * dn); oh.y = (_Float16)(o.y * dn);
        oh.z = (_Float16)(o.z * dn); oh.w = (_Float16)(o.w * dn);
        g_out[n * 8 + q] = oh;
    }
    if (blockIdx.x == 0 && tid < 8) {
        half4 z = (half4)(_Float16)0.f;
        g_out[NN * 8 + tid] = z;
    }
}

// ---------------- fused layer ----------------
template <bool LAST>
__global__ __launch_bounds__(256, 6) void k_layer(
        const half4* __restrict__ g_in,        // (NN+1) node rows, pre-scaled
        const int* __restrict__ csr,           // src ids, rows padded to x16
        const int2* __restrict__ rc,           // pos space
        const int* __restrict__ perm,          // pos -> node
        const half4* __restrict__ ni,          // pos space
        const float* __restrict__ W_dense, const float* __restrict__ b_dense,
        const float* __restrict__ b_gcn,
        const float* __restrict__ W2,          // LAST ? W_f1 : W_gcn
        const float* __restrict__ b_f1,
        const float* __restrict__ W_f2, const float* __restrict__ b_f2,
        void* __restrict__ out)                // LAST ? float logits : half4 g_out
{
    __shared__ __align__(16) float sWd[2048];
    __shared__ __align__(16) float sW2[LAST ? 2048 : 1024];
    __shared__ __align__(16) float sbd[32];
    __shared__ __align__(16) float sbg[32];
    __shared__ __align__(16) float sbf1[LAST ? 32 : 4];
    __shared__ __align__(16) float sWf2[LAST ? 64 : 4];
    __shared__ __align__(16) float sbf2[2];
    __shared__ __align__(16) _Float16 s_ni[32 * 36];
    __shared__ __align__(16) float s_t[32 * 36];

    int tid = threadIdx.x;
    for (int i = tid; i < 2048; i += 256) sWd[i] = W_dense[i];
    const int n2 = LAST ? 2048 : 1024;
    for (int i = tid; i < n2; i += 256) sW2[i] = W2[i];
    if (tid < 32) { sbd[tid] = b_dense[tid]; sbg[tid] = b_gcn[tid]; }
    if constexpr (LAST) {
        if (tid >= 64 && tid < 96) sbf1[tid - 64] = b_f1[tid - 64];
        if (tid >= 96 && tid < 160) sWf2[tid - 96] = W_f2[tid - 96];
        if (tid >= 160 && tid < 162) sbf2[tid - 160] = b_f2[tid - 160];
    }
    __syncthreads();

    int ln = tid >> 3, q = tid & 7;
    int gw = blockIdx.x + (tid >> 6) * NBLK;
    int pos = gw * 8 + ((tid >> 3) & 7);
    int2 r = rc[pos];
    int start = r.x, cnt = r.y;
    int n = perm[pos];
    float disd = rsqrtf((float)cnt + 1.0f);

    // ---- gather: acc = g'[n] + sum g'[src]; t = relu(disd*acc + b) ----
    float4 acc;
    {
        half4 gs = g_in[n * 8 + q];
        acc.x = (float)gs.x; acc.y = (float)gs.y;
        acc.z = (float)gs.z; acc.w = (float)gs.w;
    }
    int nb16 = (cnt + 15) >> 4;
    for (int b = 0; b < nb16; b++) {
        int p = start + b * 16 + q;
        int s0 = csr[p];
        int s1 = csr[p + 8];
        half4 tmp[16];
#pragma unroll
        for (int j = 0; j < 8; j++) tmp[j] = g_in[__shfl(s0, j, 8) * 8 + q];
#pragma unroll
        for (int j = 0; j < 8; j++) tmp[8 + j] = g_in[__shfl(s1, j, 8) * 8 + q];
#pragma unroll
        for (int j = 0; j < 16; j++) {
            acc.x += (float)tmp[j].x; acc.y += (float)tmp[j].y;
            acc.z += (float)tmp[j].z; acc.w += (float)tmp[j].w;
        }
    }
    float4 t;
    t.x = fmaxf(fmaf(disd, acc.x, sbg[4 * q + 0]), 0.f);
    t.y = fmaxf(fmaf(disd, acc.y, sbg[4 * q + 1]), 0.f);
    t.z = fmaxf(fmaf(disd, acc.z, sbg[4 * q + 2]), 0.f);
    t.w = fmaxf(fmaf(disd, acc.w, sbg[4 * q + 3]), 0.f);
    *(float4*)&s_t[ln * 36 + 4 * q] = t;
    *(half4*)&s_ni[ln * 36 + 4 * q] = ni[pos * 8 + q];
    __syncthreads();

    // ---- dense: h = relu(concat(ni, t) @ W_dense + b_dense) ----
    float4 a = ((const float4*)sbd)[q];
#pragma unroll
    for (int k = 0; k < 32; k++) {
        float v = (float)s_ni[ln * 36 + k];
        float4 wv = ((const float4*)sWd)[k * 8 + q];
        a.x = fmaf(v, wv.x, a.x); a.y = fmaf(v, wv.y, a.y);
        a.z = fmaf(v, wv.z, a.z); a.w = fmaf(v, wv.w, a.w);
    }
#pragma unroll
    for (int k = 0; k < 32; k++) {
        float v = s_t[ln * 36 + k];
        float4 wv = ((const float4*)sWd)[(32 + k) * 8 + q];
        a.x = fmaf(v, wv.x, a.x); a.y = fmaf(v, wv.y, a.y);
        a.z = fmaf(v, wv.z, a.z); a.w = fmaf(v, wv.w, a.w);
    }
    float4 h;
    h.x = fmaxf(a.x, 0.f); h.y = fmaxf(a.y, 0.f);
    h.z = fmaxf(a.z, 0.f); h.w = fmaxf(a.w, 0.f);
    __syncthreads();
    *(float4*)&s_t[ln * 36 + 4 * q] = h;
    __syncthreads();

    if constexpr (!LAST) {
        float4 o = make_float4(0.f, 0.f, 0.f, 0.f);
#pragma unroll
        for (int k = 0; k < 32; k++) {
            float v = s_t[ln * 36 + k];
            float4 wv = ((const float4*)sW2)[k * 8 + q];
            o.x = fmaf(v, wv.x, o.x); o.y = fmaf(v, wv.y, o.y);
            o.z = fmaf(v, wv.z, o.z); o.w = fmaf(v, wv.w, o.w);
        }
        if (n < NN) {
            half4 oh;
            oh.x = (_Float16)(o.x * disd); oh.y = (_Float16)(o.y * disd);
            oh.z = (_Float16)(o.z * disd); oh.w = (_Float16)(o.w * disd);
            ((half4*)out)[n * 8 + q] = oh;
        }
        if (blockIdx.x == 0 && tid < 8) {
            half4 z = (half4)(_Float16)0.f;
            ((half4*)out)[NN * 8 + tid] = z;
        }
    } else {
        float4 a2v = ((const float4*)sbf1)[q];
#pragma unroll
        for (int k = 0; k < 32; k++) {
            float v = (float)s_ni[ln * 36 + k];
            float4 wv = ((const float4*)sW2)[k * 8 + q];
            a2v.x = fmaf(v, wv.x, a2v.x); a2v.y = fmaf(v, wv.y, a2v.y);
            a2v.z = fmaf(v, wv.z, a2v.z); a2v.w = fmaf(v, wv.w, a2v.w);
        }
#pragma unroll
        for (int k = 0; k < 32; k++) {
            float v = s_t[ln * 36 + k];
            float4 wv = ((const float4*)sW2)[(32 + k) * 8 + q];
            a2v.x = fmaf(v, wv.x, a2v.x); a2v.y = fmaf(v, wv.y, a2v.y);
            a2v.z = fmaf(v, wv.z, a2v.z); a2v.w = fmaf(v, wv.w, a2v.w);
        }
        float4 u;
        u.x = fmaxf(a2v.x, 0.f); u.y = fmaxf(a2v.y, 0.f);
        u.z = fmaxf(a2v.z, 0.f); u.w = fmaxf(a2v.w, 0.f);
        float p0 = u.x * sWf2[(4 * q + 0) * 2 + 0] + u.y * sWf2[(4 * q + 1) * 2 + 0]
                 + u.z * sWf2[(4 * q + 2) * 2 + 0] + u.w * sWf2[(4 * q + 3) * 2 + 0];
        float p1 = u.x * sWf2[(4 * q + 0) * 2 + 1] + u.y * sWf2[(4 * q + 1) * 2 + 1]
                 + u.z * sWf2[(4 * q + 2) * 2 + 1] + u.w * sWf2[(4 * q + 3) * 2 + 1];
        p0 += __shfl_down(p0, 4, 8); p1 += __shfl_down(p1, 4, 8);
        p0 += __shfl_down(p0, 2, 8); p1 += __shfl_down(p1, 2, 8);
        p0 += __shfl_down(p0, 1, 8); p1 += __shfl_down(p1, 1, 8);
        if (q == 0 && n < NN) {
            ((float*)out)[n * 2 + 0] = p0 + sbf2[0];
            ((float*)out)[n * 2 + 1] = p1 + sbf2[1];
        }
    }
}

// ---------------- launch ----------------

extern "C" void kernel_launch(void* const* d_in, const int* in_sizes, int n_in,
                              void* d_out, int out_size, void* d_ws, size_t ws_size,
                              hipStream_t stream) {
    const float* x      = (const float*)d_in[0];
    const int*   ei     = (const int*)d_in[1];
    const float* W_pre  = (const float*)d_in[2];
    const float* b_pre  = (const float*)d_in[3];
    const float* W_fc1  = (const float*)d_in[4];
    const float* b_fc1  = (const float*)d_in[5];
    const float* W_fc2  = (const float*)d_in[6];
    const float* b_fc2  = (const float*)d_in[7];
    const float* W_gcn  = (const float*)d_in[8];
    const float* b_gcn  = (const float*)d_in[9];
    const float* W_dense= (const float*)d_in[10];
    const float* b_dense= (const float*)d_in[11];
    const float* W_f1   = (const float*)d_in[12];
    const float* b_f1   = (const float*)d_in[13];
    const float* W_f2   = (const float*)d_in[14];
    const float* b_f2   = (const float*)d_in[15];

    const int* src = ei;
    const int* dst = ei + NE;

    size_t off = 0;
    auto alloc = [&](size_t bytes) -> void* {
        off = (off + 255) & ~(size_t)255;
        void* p = (char*)d_ws + off;
        off += bytes;
        return p;
    };
    int2*  rc      = (int2*) alloc((size_t)NP * sizeof(int2));
    int*   perm    = (int*)  alloc((size_t)NP * sizeof(int));
    int*   gcur    = (int*)  alloc(NB * sizeof(int));
    int*   csr     = (int*)  alloc((size_t)NB * CAPE * sizeof(int));    // 20.9 MB
    // bin (16.05 MB) overlays gA+gB (2 x 6.4 MB fp16): bin dead before preproc.
    char*  Ureg    = (char*) alloc((size_t)NB * CAPB * sizeof(unsigned));
    half4* ni      = (half4*)alloc((size_t)NP * 32 * sizeof(_Float16));
    unsigned* bin  = (unsigned*)Ureg;
    half4* gA      = (half4*)Ureg;
    half4* gB      = (half4*)(Ureg + (size_t)(NN + 1) * 32 * sizeof(_Float16));

    const int binBlocks   = (NE + EPB - 1) / EPB; // 391

    k_init_gcur<<<1, 512, 0, stream>>>(gcur);
    k_bin<<<binBlocks, 512, 0, stream>>>(src, dst, gcur, bin);
    k_build<<<NB, 1024, 0, stream>>>(gcur, bin, rc, perm, csr);

    k_preproc<<<NBLK, 256, 0, stream>>>(x, W_pre, b_pre, W_fc1, b_fc1,
                                        W_fc2, b_fc2, W_gcn, perm, rc, ni, gA);

    half4* gin = gA;
    half4* gout = gB;
    for (int l = 0; l < 5; l++) {
        k_layer<false><<<NBLK, 256, 0, stream>>>(
            gin, csr, rc, perm, ni, W_dense, b_dense, b_gcn,
            W_gcn, nullptr, nullptr, nullptr, (void*)gout);
        half4* tmp = gin; gin = gout; gout = tmp;
    }
    k_layer<true><<<NBLK, 256, 0, stream>>>(
        gin, csr, rc, perm, ni, W_dense, b_dense, b_gcn,
        W_f1, b_f1, W_f2, b_f2, d_out);
}

// Round 11
// 416.284 us; speedup vs baseline: 1.1332x; 1.0368x over previous
//
#include <hip/hip_runtime.h>
#include <math.h>

#define NN 100000
#define NE 3200000
#define NB 196          // dst-buckets of 512 nodes: 196*512 = 100352 >= NN
#define NP (NB * 512)   // pos space (100352)
#define CAPB 20480      // bin entries per bucket (mean 16327 + 32 sigma)
#define CAPE 26624      // csr slots per bucket (edges + <=15 pad/row)
#define EPB 4096        // edges per k_bin slab (782 blocks -> 3 blocks/CU)
#define NBLK 3136       // layer grid (NP/32)
#define WPB 8           // waves per k_bin block

typedef _Float16 half4 __attribute__((ext_vector_type(4)));
typedef _Float16 half2t __attribute__((ext_vector_type(2)));

// Degree-sorted pos space (perm[pos] -> node) with x16-padded rows (sentinel NN).
// Layers: balanced wave interleave; dense/transform via v_dot2_f32_f16 with
// fp16 weight pairs in LDS; head (W_f1/W_f2) kept fp32 for accuracy.

// ---------------- binned CSR build ----------------

__global__ __launch_bounds__(512) void k_init_gcur(int* gcur) {
    int i = threadIdx.x;
    if (i < NB) gcur[i] = i * CAPB;
}

__global__ __launch_bounds__(512) void k_bin(const int* __restrict__ src,
                                             const int* __restrict__ dst,
                                             int* __restrict__ gcur,
                                             unsigned* __restrict__ bin) {
    __shared__ int h8[WPB][NB];     // per-wave histogram / cursor
    __shared__ int b8[WPB][NB];     // per-wave scatter base
    int tid = threadIdx.x;
    int w = tid >> 6;
    for (int i = tid; i < WPB * NB; i += 512) ((int*)h8)[i] = 0;
    __syncthreads();
    int e0 = blockIdx.x * EPB;
    int dcache[EPB / 512];
#pragma unroll
    for (int i = 0; i < EPB / 512; i++) {
        int e = e0 + i * 512 + tid;
        dcache[i] = (e < NE) ? dst[e] : -1;
        if (dcache[i] >= 0) atomicAdd(&h8[w][dcache[i] >> 9], 1);
    }
    __syncthreads();
    for (int b = tid; b < NB; b += 512) {
        int tot = 0;
#pragma unroll
        for (int ww = 0; ww < WPB; ww++) tot += h8[ww][b];
        int run = (tot > 0) ? atomicAdd(&gcur[b], tot) : 0;
#pragma unroll
        for (int ww = 0; ww < WPB; ww++) { b8[ww][b] = run; run += h8[ww][b]; }
    }
    __syncthreads();
    for (int i = tid; i < WPB * NB; i += 512) ((int*)h8)[i] = 0;
    __syncthreads();
#pragma unroll
    for (int i = 0; i < EPB / 512; i++) {
        int e = e0 + i * 512 + tid;
        int d = dcache[i];
        if (d >= 0) {
            int b = d >> 9;
            int pos = b8[w][b] + atomicAdd(&h8[w][b], 1);
            bin[pos] = ((unsigned)src[e] << 9) | (unsigned)(d & 511);
        }
    }
}

// Per-bucket: degree hist -> counting sort by degree -> row layout -> scatter.
__global__ __launch_bounds__(1024) void k_build(const int* __restrict__ gcur,
                                                const unsigned* __restrict__ bin,
                                                int2* __restrict__ rc,
                                                int* __restrict__ perm,
                                                int* __restrict__ csr) {
    __shared__ int deg[512];
    __shared__ int rank[512];
    __shared__ int dhist[128];
    __shared__ int dbase[128];
    __shared__ int sz[512];
    __shared__ int rowst[512];
    int b = blockIdx.x, tid = threadIdx.x;
    if (tid < 512) deg[tid] = 0;
    if (tid < 128) dhist[tid] = 0;
    __syncthreads();
    int base = b * CAPB, cnt = gcur[b] - base;
    for (int i = tid; i < cnt; i += 1024) atomicAdd(&deg[bin[base + i] & 511], 1);
    __syncthreads();
    int node = b * 512 + (tid & 511);
    int myDeg = 0, myKey = 127, myPad = 0;
    if (tid < 512) {
        myDeg = deg[tid];
        myKey = (node < NN) ? min(myDeg, 126) : 127;
        atomicAdd(&dhist[myKey], 1);
    }
    __syncthreads();
    if (tid < 128) dbase[tid] = dhist[tid];
    __syncthreads();
    for (int off = 1; off < 128; off <<= 1) {
        int t = 0;
        if (tid < 128 && tid >= off) t = dbase[tid - off];
        __syncthreads();
        if (tid < 128) dbase[tid] += t;
        __syncthreads();
    }
    if (tid < 128) dbase[tid] -= dhist[tid];
    __syncthreads();
    if (tid < 128) dhist[tid] = 0;
    __syncthreads();
    if (tid < 512) {
        int r = dbase[myKey] + atomicAdd(&dhist[myKey], 1);
        rank[tid] = r;
        myPad = (node < NN) ? ((myDeg + 15) & ~15) : 0;
        sz[r] = myPad;
    }
    __syncthreads();
    for (int off = 1; off < 512; off <<= 1) {
        int t = 0;
        if (tid < 512 && tid >= off) t = sz[tid - off];
        __syncthreads();
        if (tid < 512) sz[tid] += t;
        __syncthreads();
    }
    if (tid < 512) {
        int excl = sz[rank[tid]] - myPad;
        int rs = b * CAPE + excl;
        rowst[tid] = rs;
        int pos = b * 512 + rank[tid];
        rc[pos] = make_int2(rs, (node < NN) ? myDeg : 0);
        perm[pos] = (node < NN) ? node : NN;
    }
    __syncthreads();
    if (tid < 512) deg[tid] = rowst[tid];
    __syncthreads();
    for (int i = tid; i < cnt; i += 1024) {
        unsigned u = bin[base + i];
        int dl = u & 511;
        int pos = atomicAdd(&deg[dl], 1);
        csr[pos] = (int)(u >> 9);
    }
    __syncthreads();
    if (tid < 512 && node < NN) {
        int end = rowst[tid] + myPad;
        for (int i = deg[tid]; i < end; i++) csr[i] = NN;
    }
}

// ---------------- fused preproc (+ first GCN transform, pre-scaled) ----------------
__global__ __launch_bounds__(256) void k_preproc(
        const float* __restrict__ x,
        const float* __restrict__ W_pre, const float* __restrict__ b_pre,
        const float* __restrict__ W_fc1, const float* __restrict__ b_fc1,
        const float* __restrict__ W_fc2, const float* __restrict__ b_fc2,
        const float* __restrict__ W_gcn,
        const int* __restrict__ perm, const int2* __restrict__ rc,
        half4* __restrict__ ni, half4* __restrict__ g_out) {
    __shared__ __align__(16) float sWp[60];
    __shared__ __align__(16) float sbp[12];
    __shared__ __align__(16) float sW1[320];
    __shared__ __align__(16) float sb1[32];
    __shared__ __align__(16) float sW2[320];
    __shared__ __align__(16) float sb2[32];
    __shared__ __align__(16) float sWg[1024];
    __shared__ __align__(16) float s_h[32 * 36];
    int tid = threadIdx.x;
    if (tid < 60) sWp[tid] = W_pre[tid];
    if (tid >= 64 && tid < 74) sbp[tid - 64] = b_pre[tid - 64];
    for (int i = tid; i < 320; i += 256) { sW1[i] = W_fc1[i]; sW2[i] = W_fc2[i]; }
    if (tid >= 96 && tid < 128) sb1[tid - 96] = b_fc1[tid - 96];
    if (tid >= 128 && tid < 160) sb2[tid - 128] = b_fc2[tid - 128];
    for (int i = tid; i < 1024; i += 256) sWg[i] = W_gcn[i];
    __syncthreads();

    int ln = tid >> 3, q = tid & 7;
    int pos = blockIdx.x * 32 + ln;
    int n = perm[pos];
    int2 r = rc[pos];
    float dn = rsqrtf((float)r.y + 1.0f);
    int nx = (n < NN) ? n : 0;

    float xv[6];
#pragma unroll
    for (int k = 0; k < 6; k++) xv[k] = x[nx * 6 + k];
    float p[10];
#pragma unroll
    for (int j = 0; j < 10; j++) {
        float a = sbp[j];
#pragma unroll
        for (int k = 0; k < 6; k++) a = fmaf(xv[k], sWp[k * 10 + j], a);
        p[j] = 1.0f / (1.0f + expf(-a));
    }
    float4 a1 = ((const float4*)sb1)[q];
    float4 a2 = ((const float4*)sb2)[q];
#pragma unroll
    for (int k = 0; k < 10; k++) {
        float4 w1 = ((const float4*)sW1)[k * 8 + q];
        float4 w2 = ((const float4*)sW2)[k * 8 + q];
        a1.x = fmaf(p[k], w1.x, a1.x); a1.y = fmaf(p[k], w1.y, a1.y);
        a1.z = fmaf(p[k], w1.z, a1.z); a1.w = fmaf(p[k], w1.w, a1.w);
        a2.x = fmaf(p[k], w2.x, a2.x); a2.y = fmaf(p[k], w2.y, a2.y);
        a2.z = fmaf(p[k], w2.z, a2.z); a2.w = fmaf(p[k], w2.w, a2.w);
    }
    half4 niv;
    niv.x = (_Float16)fmaxf(a1.x, 0.f); niv.y = (_Float16)fmaxf(a1.y, 0.f);
    niv.z = (_Float16)fmaxf(a1.z, 0.f); niv.w = (_Float16)fmaxf(a1.w, 0.f);
    ni[pos * 8 + q] = niv;
    float4 hv;
    hv.x = fmaxf(a2.x, 0.f); hv.y = fmaxf(a2.y, 0.f);
    hv.z = fmaxf(a2.z, 0.f); hv.w = fmaxf(a2.w, 0.f);
    *(float4*)&s_h[ln * 36 + 4 * q] = hv;
    __syncthreads();
    float4 o = make_float4(0.f, 0.f, 0.f, 0.f);
#pragma unroll
    for (int k = 0; k < 32; k++) {
        float v = s_h[ln * 36 + k];
        float4 wv = ((const float4*)sWg)[k * 8 + q];
        o.x = fmaf(v, wv.x, o.x); o.y = fmaf(v, wv.y, o.y);
        o.z = fmaf(v, wv.z, o.z); o.w = fmaf(v, wv.w, o.w);
    }
    if (n < NN) {
        half4 oh;
        oh.x = (_Float16)(o.x * dn); oh.y = (_Float16)(o.y * dn);
        oh.z = (_Float16)(o.z * dn); oh.w = (_Float16)(o.w * dn);
        g_out[n * 8 + q] = oh;
    }
    if (blockIdx.x == 0 && tid < 8) {
        half4 z = (half4)(_Float16)0.f;
        g_out[NN * 8 + tid] = z;
    }
}

// ---------------- fused layer (fdot2 dense/transform) ----------------
template <bool LAST>
__global__ __launch_bounds__(256, 6) void k_layer(
        const half4* __restrict__ g_in,        // (NN+1) node rows, pre-scaled
        const int* __restrict__ csr,           // src ids, rows padded to x16
        const int2* __restrict__ rc,           // pos space
        const int* __restrict__ perm,          // pos -> node
        const half4* __restrict__ ni,          // pos space
        const float* __restrict__ W_dense, const float* __restrict__ b_dense,
        const float* __restrict__ b_gcn,
        const float* __restrict__ W2,          // LAST ? W_f1 : W_gcn
        const float* __restrict__ b_f1,
        const float* __restrict__ W_f2, const float* __restrict__ b_f2,
        void* __restrict__ out)                // LAST ? float logits : half4 g_out
{
    __shared__ __align__(16) half2t sWd2[1024];               // W_dense pairs (fp16)
    __shared__ __align__(16) half2t sWg2[LAST ? 4 : 512];     // W_gcn pairs (fp16)
    __shared__ __align__(16) float sWf1[LAST ? 2048 : 4];     // W_f1 fp32
    __shared__ __align__(16) float sbd[32];
    __shared__ __align__(16) float sbg[32];
    __shared__ __align__(16) float sbf1[LAST ? 32 : 4];
    __shared__ __align__(16) float sWf2[LAST ? 64 : 4];
    __shared__ __align__(16) float sbf2[2];
    __shared__ __align__(16) _Float16 s_ni[32 * 40];
    __shared__ __align__(16) _Float16 s_t[32 * 40];

    int tid = threadIdx.x;
    for (int i = tid; i < 1024; i += 256) {
        int kk = i >> 5, c = i & 31;
        sWd2[i] = half2t{(_Float16)W_dense[(2 * kk) * 32 + c],
                         (_Float16)W_dense[(2 * kk + 1) * 32 + c]};
    }
    if constexpr (!LAST) {
        for (int i = tid; i < 512; i += 256) {
            int kk = i >> 5, c = i & 31;
            sWg2[i] = half2t{(_Float16)W2[(2 * kk) * 32 + c],
                             (_Float16)W2[(2 * kk + 1) * 32 + c]};
        }
    } else {
        for (int i = tid; i < 2048; i += 256) sWf1[i] = W2[i];
        if (tid >= 64 && tid < 96) sbf1[tid - 64] = b_f1[tid - 64];
        if (tid >= 96 && tid < 160) sWf2[tid - 96] = W_f2[tid - 96];
        if (tid >= 160 && tid < 162) sbf2[tid - 160] = b_f2[tid - 160];
    }
    if (tid < 32) { sbd[tid] = b_dense[tid]; sbg[tid] = b_gcn[tid]; }
    __syncthreads();

    int ln = tid >> 3, q = tid & 7;
    int gw = blockIdx.x + (tid >> 6) * NBLK;
    int pos = gw * 8 + ((tid >> 3) & 7);
    int2 r = rc[pos];
    int start = r.x, cnt = r.y;
    int n = perm[pos];
    float disd = rsqrtf((float)cnt + 1.0f);

    // ---- gather: acc = g'[n] + sum g'[src]; t = relu(disd*acc + b) ----
    float4 acc;
    {
        half4 gs = g_in[n * 8 + q];
        acc.x = (float)gs.x; acc.y = (float)gs.y;
        acc.z = (float)gs.z; acc.w = (float)gs.w;
    }
    int nb16 = (cnt + 15) >> 4;
    int p = start + q;
    int s0 = 0, s1 = 0;
    if (nb16 > 0) { s0 = csr[p]; s1 = csr[p + 8]; }
    for (int b = 0; b < nb16; b++) {
        int ns0 = 0, ns1 = 0;
        if (b + 1 < nb16) { ns0 = csr[p + 16]; ns1 = csr[p + 24]; }
        half4 tmp[16];
#pragma unroll
        for (int j = 0; j < 8; j++) tmp[j] = g_in[__shfl(s0, j, 8) * 8 + q];
#pragma unroll
        for (int j = 0; j < 8; j++) tmp[8 + j] = g_in[__shfl(s1, j, 8) * 8 + q];
#pragma unroll
        for (int j = 0; j < 16; j++) {
            acc.x += (float)tmp[j].x; acc.y += (float)tmp[j].y;
            acc.z += (float)tmp[j].z; acc.w += (float)tmp[j].w;
        }
        s0 = ns0; s1 = ns1; p += 16;
    }
    {
        half4 t;
        t.x = (_Float16)fmaxf(fmaf(disd, acc.x, sbg[4 * q + 0]), 0.f);
        t.y = (_Float16)fmaxf(fmaf(disd, acc.y, sbg[4 * q + 1]), 0.f);
        t.z = (_Float16)fmaxf(fmaf(disd, acc.z, sbg[4 * q + 2]), 0.f);
        t.w = (_Float16)fmaxf(fmaf(disd, acc.w, sbg[4 * q + 3]), 0.f);
        *(half4*)&s_t[ln * 40 + 4 * q] = t;
    }
    *(half4*)&s_ni[ln * 40 + 4 * q] = ni[pos * 8 + q];
    __syncthreads();

    // ---- dense: h = relu(concat(ni, t) @ W_dense + b_dense), via fdot2 ----
    float4 a = ((const float4*)sbd)[q];
#pragma unroll
    for (int kk = 0; kk < 16; kk++) {
        half2t in2 = *(half2t*)&s_ni[ln * 40 + 2 * kk];
        a.x = __builtin_amdgcn_fdot2(in2, sWd2[kk * 32 + 4 * q + 0], a.x, false);
        a.y = __builtin_amdgcn_fdot2(in2, sWd2[kk * 32 + 4 * q + 1], a.y, false);
        a.z = __builtin_amdgcn_fdot2(in2, sWd2[kk * 32 + 4 * q + 2], a.z, false);
        a.w = __builtin_amdgcn_fdot2(in2, sWd2[kk * 32 + 4 * q + 3], a.w, false);
    }
#pragma unroll
    for (int kk = 0; kk < 16; kk++) {
        half2t in2 = *(half2t*)&s_t[ln * 40 + 2 * kk];
        a.x = __builtin_amdgcn_fdot2(in2, sWd2[(16 + kk) * 32 + 4 * q + 0], a.x, false);
        a.y = __builtin_amdgcn_fdot2(in2, sWd2[(16 + kk) * 32 + 4 * q + 1], a.y, false);
        a.z = __builtin_amdgcn_fdot2(in2, sWd2[(16 + kk) * 32 + 4 * q + 2], a.z, false);
        a.w = __builtin_amdgcn_fdot2(in2, sWd2[(16 + kk) * 32 + 4 * q + 3], a.w, false);
    }
    half4 h;
    h.x = (_Float16)fmaxf(a.x, 0.f); h.y = (_Float16)fmaxf(a.y, 0.f);
    h.z = (_Float16)fmaxf(a.z, 0.f); h.w = (_Float16)fmaxf(a.w, 0.f);
    __syncthreads();
    *(half4*)&s_t[ln * 40 + 4 * q] = h;
    __syncthreads();

    if constexpr (!LAST) {
        // ---- transform + pre-scale: g'_out = disd * (h @ W_gcn), via fdot2 ----
        float4 o = make_float4(0.f, 0.f, 0.f, 0.f);
#pragma unroll
        for (int kk = 0; kk < 16; kk++) {
            half2t in2 = *(half2t*)&s_t[ln * 40 + 2 * kk];
            o.x = __builtin_amdgcn_fdot2(in2, sWg2[kk * 32 + 4 * q + 0], o.x, false);
            o.y = __builtin_amdgcn_fdot2(in2, sWg2[kk * 32 + 4 * q + 1], o.y, false);
            o.z = __builtin_amdgcn_fdot2(in2, sWg2[kk * 32 + 4 * q + 2], o.z, false);
            o.w = __builtin_amdgcn_fdot2(in2, sWg2[kk * 32 + 4 * q + 3], o.w, false);
        }
        if (n < NN) {
            half4 oh;
            oh.x = (_Float16)(o.x * disd); oh.y = (_Float16)(o.y * disd);
            oh.z = (_Float16)(o.z * disd); oh.w = (_Float16)(o.w * disd);
            ((half4*)out)[n * 8 + q] = oh;
        }
        if (blockIdx.x == 0 && tid < 8) {
            half4 z = (half4)(_Float16)0.f;
            ((half4*)out)[NN * 8 + tid] = z;
        }
    } else {
        // ---- head in fp32: u = relu(concat(ni,h)@W_f1+b); out = u@W_f2+b ----
        float4 a2v = ((const float4*)sbf1)[q];
#pragma unroll
        for (int k = 0; k < 32; k++) {
            float v = (float)s_ni[ln * 40 + k];
            float4 wv = ((const float4*)sWf1)[k * 8 + q];
            a2v.x = fmaf(v, wv.x, a2v.x); a2v.y = fmaf(v, wv.y, a2v.y);
            a2v.z = fmaf(v, wv.z, a2v.z); a2v.w = fmaf(v, wv.w, a2v.w);
        }
#pragma unroll
        for (int k = 0; k < 32; k++) {
            float v = (float)s_t[ln * 40 + k];
            float4 wv = ((const float4*)sWf1)[(32 + k) * 8 + q];
            a2v.x = fmaf(v, wv.x, a2v.x); a2v.y = fmaf(v, wv.y, a2v.y);
            a2v.z = fmaf(v, wv.z, a2v.z); a2v.w = fmaf(v, wv.w, a2v.w);
        }
        float4 u;
        u.x = fmaxf(a2v.x, 0.f); u.y = fmaxf(a2v.y, 0.f);
        u.z = fmaxf(a2v.z, 0.f); u.w = fmaxf(a2v.w, 0.f);
        float p0 = u.x * sWf2[(4 * q + 0) * 2 + 0] + u.y * sWf2[(4 * q + 1) * 2 + 0]
                 + u.z * sWf2[(4 * q + 2) * 2 + 0] + u.w * sWf2[(4 * q + 3) * 2 + 0];
        float p1 = u.x * sWf2[(4 * q + 0) * 2 + 1] + u.y * sWf2[(4 * q + 1) * 2 + 1]
                 + u.z * sWf2[(4 * q + 2) * 2 + 1] + u.w * sWf2[(4 * q + 3) * 2 + 1];
        p0 += __shfl_down(p0, 4, 8); p1 += __shfl_down(p1, 4, 8);
        p0 += __shfl_down(p0, 2, 8); p1 += __shfl_down(p1, 2, 8);
        p0 += __shfl_down(p0, 1, 8); p1 += __shfl_down(p1, 1, 8);
        if (q == 0 && n < NN) {
            ((float*)out)[n * 2 + 0] = p0 + sbf2[0];
            ((float*)out)[n * 2 + 1] = p1 + sbf2[1];
        }
    }
}

// ---------------- launch ----------------

extern "C" void kernel_launch(void* const* d_in, const int* in_sizes, int n_in,
                              void* d_out, int out_size, void* d_ws, size_t ws_size,
                              hipStream_t stream) {
    const float* x      = (const float*)d_in[0];
    const int*   ei     = (const int*)d_in[1];
    const float* W_pre  = (const float*)d_in[2];
    const float* b_pre  = (const float*)d_in[3];
    const float* W_fc1  = (const float*)d_in[4];
    const float* b_fc1  = (const float*)d_in[5];
    const float* W_fc2  = (const float*)d_in[6];
    const float* b_fc2  = (const float*)d_in[7];
    const float* W_gcn  = (const float*)d_in[8];
    const float* b_gcn  = (const float*)d_in[9];
    const float* W_dense= (const float*)d_in[10];
    const float* b_dense= (const float*)d_in[11];
    const float* W_f1   = (const float*)d_in[12];
    const float* b_f1   = (const float*)d_in[13];
    const float* W_f2   = (const float*)d_in[14];
    const float* b_f2   = (const float*)d_in[15];

    const int* src = ei;
    const int* dst = ei + NE;

    size_t off = 0;
    auto alloc = [&](size_t bytes) -> void* {
        off = (off + 255) & ~(size_t)255;
        void* p = (char*)d_ws + off;
        off += bytes;
        return p;
    };
    int2*  rc      = (int2*) alloc((size_t)NP * sizeof(int2));
    int*   perm    = (int*)  alloc((size_t)NP * sizeof(int));
    int*   gcur    = (int*)  alloc(NB * sizeof(int));
    int*   csr     = (int*)  alloc((size_t)NB * CAPE * sizeof(int));    // 20.9 MB
    // bin (16.05 MB) overlays gA+gB (2 x 6.4 MB fp16): bin dead before preproc.
    char*  Ureg    = (char*) alloc((size_t)NB * CAPB * sizeof(unsigned));
    half4* ni      = (half4*)alloc((size_t)NP * 32 * sizeof(_Float16));
    unsigned* bin  = (unsigned*)Ureg;
    half4* gA      = (half4*)Ureg;
    half4* gB      = (half4*)(Ureg + (size_t)(NN + 1) * 32 * sizeof(_Float16));

    const int binBlocks   = (NE + EPB - 1) / EPB; // 782

    k_init_gcur<<<1, 512, 0, stream>>>(gcur);
    k_bin<<<binBlocks, 512, 0, stream>>>(src, dst, gcur, bin);
    k_build<<<NB, 1024, 0, stream>>>(gcur, bin, rc, perm, csr);

    k_preproc<<<NBLK, 256, 0, stream>>>(x, W_pre, b_pre, W_fc1, b_fc1,
                                        W_fc2, b_fc2, W_gcn, perm, rc, ni, gA);

    half4* gin = gA;
    half4* gout = gB;
    for (int l = 0; l < 5; l++) {
        k_layer<false><<<NBLK, 256, 0, stream>>>(
            gin, csr, rc, perm, ni, W_dense, b_dense, b_gcn,
            W_gcn, nullptr, nullptr, nullptr, (void*)gout);
        half4* tmp = gin; gin = gout; gout = tmp;
    }
    k_layer<true><<<NBLK, 256, 0, stream>>>(
        gin, csr, rc, perm, ni, W_dense, b_dense, b_gcn,
        W_f1, b_f1, W_f2, b_f2, d_out);
}